// Round 2
// baseline (1863.749 us; speedup 1.0000x reference)
//
#include <hip/hip_runtime.h>
#include <hip/hip_bf16.h>
#include <cstdint>
#include <cstddef>

// ---------- helpers ----------
__device__ __forceinline__ float bf2f(unsigned short u) {
    return __uint_as_float(((unsigned int)u) << 16);
}
__device__ __forceinline__ unsigned short f2bf(float f) {
    unsigned int u = __float_as_uint(f);
    unsigned int r = (u + 0x7fff + ((u >> 16) & 1)) >> 16;
    return (unsigned short)r;
}

template <typename AT>
__device__ __forceinline__ void load4f(const AT* p, float o[4]);
template <>
__device__ __forceinline__ void load4f<unsigned short>(const unsigned short* p, float o[4]) {
    ushort4 v = *reinterpret_cast<const ushort4*>(p);
    o[0] = bf2f(v.x); o[1] = bf2f(v.y); o[2] = bf2f(v.z); o[3] = bf2f(v.w);
}
template <>
__device__ __forceinline__ void load4f<float>(const float* p, float o[4]) {
    float4 v = *reinterpret_cast<const float4*>(p);
    o[0] = v.x; o[1] = v.y; o[2] = v.z; o[3] = v.w;
}

// ---------- CSR build ----------
__global__ __launch_bounds__(256) void hist_kernel(const int* __restrict__ dst, int E,
                                                   int* __restrict__ deg) {
    int i = blockIdx.x * blockDim.x + threadIdx.x;
    int stride = gridDim.x * blockDim.x;
    for (int e = i; e < E; e += stride) atomicAdd(&deg[dst[e]], 1);
}

// single-block scan: 256 threads x 16 elems/thread per iteration (4096/iter)
__global__ __launch_bounds__(256) void scan_kernel(const int* __restrict__ deg,
                                                   int* __restrict__ rowptr, int n) {
    __shared__ int wsum[4];
    __shared__ int carry_s;
    int tid = threadIdx.x, lane = tid & 63, wave = tid >> 6;
    if (tid == 0) carry_s = 0;
    __syncthreads();
    const int CHUNK = 16;
    const int PER_ITER = 256 * CHUNK;  // 4096
    for (int base = 0; base < n; base += PER_ITER) {
        int idx0 = base + tid * CHUNK;
        int v[CHUNK];
        int s = 0;
        #pragma unroll
        for (int j = 0; j < CHUNK; ++j) {
            int i = idx0 + j;
            v[j] = (i < n) ? deg[i] : 0;
            s += v[j];
        }
        // inclusive wave scan of per-thread sums
        int inc = s;
        #pragma unroll
        for (int off = 1; off < 64; off <<= 1) {
            int t = __shfl_up(inc, off, 64);
            if (lane >= off) inc += t;
        }
        if (lane == 63) wsum[wave] = inc;
        __syncthreads();  // A: wsum visible
        int wbase = 0;
        #pragma unroll
        for (int w = 0; w < 4; ++w)
            if (w < wave) wbase += wsum[w];
        int total_iter = wsum[0] + wsum[1] + wsum[2] + wsum[3];
        int carry = carry_s;
        __syncthreads();  // B: all have read carry_s/wsum
        if (tid == 0) carry_s = carry + total_iter;
        int run = carry + wbase + (inc - s);  // exclusive base for this thread's chunk
        #pragma unroll
        for (int j = 0; j < CHUNK; ++j) {
            int i = idx0 + j;
            if (i < n) rowptr[i] = run;
            run += v[j];
        }
        __syncthreads();  // C: carry_s update visible before next iter reads
    }
    if (tid == 0) rowptr[n] = carry_s;
}

__global__ __launch_bounds__(256) void dinv_kernel(const int* __restrict__ deg,
                                                   float* __restrict__ dinv, int n) {
    int i = blockIdx.x * blockDim.x + threadIdx.x;
    if (i < n) dinv[i] = rsqrtf((float)deg[i] + 1.0f);  // +1 self loop
}

__global__ __launch_bounds__(256) void fill_kernel(const int* __restrict__ eidx, int E,
                                                   int* __restrict__ cursor,
                                                   int* __restrict__ csr_src) {
    int e = blockIdx.x * blockDim.x + threadIdx.x;
    if (e < E) {
        int s = eidx[e];
        int d = eidx[E + e];
        int pos = atomicAdd(&cursor[d], 1);
        csr_src[pos] = s;
    }
}

// ---------- fp32-accumulate tiled GEMM: C[M,N](bf16) = A[M,K] * B[K,N](f32) ----------
template <typename AT>
__global__ __launch_bounds__(256) void gemm_kernel(const AT* __restrict__ A,
                                                   const float* __restrict__ B,
                                                   unsigned short* __restrict__ C,
                                                   int M, int N, int K) {
    __shared__ float As[16][68];  // A tile transposed, padded
    __shared__ float Bs[16][68];
    int tid = threadIdx.x;
    int tx = tid & 15, ty = tid >> 4;
    int m0 = blockIdx.y * 64;
    int n0 = blockIdx.x * 64;
    float acc[4][4] = {};
    int ar = tid >> 2, ac = (tid & 3) * 4;    // A tile: 64 rows x 16 cols
    int br = tid >> 4, bc = (tid & 15) * 4;   // B tile: 16 rows x 64 cols
    for (int k0 = 0; k0 < K; k0 += 16) {
        float av[4] = {0.f, 0.f, 0.f, 0.f};
        if (m0 + ar < M) load4f<AT>(A + (size_t)(m0 + ar) * K + k0 + ac, av);
        float bv[4];
        load4f<float>(B + (size_t)(k0 + br) * N + n0 + bc, bv);
        As[ac + 0][ar] = av[0]; As[ac + 1][ar] = av[1];
        As[ac + 2][ar] = av[2]; As[ac + 3][ar] = av[3];
        Bs[br][bc + 0] = bv[0]; Bs[br][bc + 1] = bv[1];
        Bs[br][bc + 2] = bv[2]; Bs[br][bc + 3] = bv[3];
        __syncthreads();
        #pragma unroll
        for (int k = 0; k < 16; ++k) {
            float a[4], b[4];
            #pragma unroll
            for (int i = 0; i < 4; ++i) a[i] = As[k][ty * 4 + i];
            #pragma unroll
            for (int j = 0; j < 4; ++j) b[j] = Bs[k][tx * 4 + j];
            #pragma unroll
            for (int i = 0; i < 4; ++i)
                #pragma unroll
                for (int j = 0; j < 4; ++j) acc[i][j] = fmaf(a[i], b[j], acc[i][j]);
        }
        __syncthreads();
    }
    #pragma unroll
    for (int i = 0; i < 4; ++i) {
        int gr = m0 + ty * 4 + i;
        if (gr < M) {
            ushort4 o;
            o.x = f2bf(acc[i][0]); o.y = f2bf(acc[i][1]);
            o.z = f2bf(acc[i][2]); o.w = f2bf(acc[i][3]);
            *reinterpret_cast<ushort4*>(&C[(size_t)gr * N + n0 + tx * 4]) = o;
        }
    }
}

// ---------- aggregation: out[i] = relu( sum_{e:dst=i} h[src]*dinv[src]*dinv[i]
//                                        + h[i]*dinv[i]^2 + bias ) ----------
// h stored bf16 [n,H]; LANES lanes per node, each lane owns 4 features (H=LANES*4).
template <int LANES>
__global__ __launch_bounds__(256) void agg_kernel(const unsigned short* __restrict__ hpre,
                                                  const float* __restrict__ dinv,
                                                  const int* __restrict__ rowptr,
                                                  const int* __restrict__ csr_src,
                                                  const float* __restrict__ bias,
                                                  unsigned short* __restrict__ hout, int n) {
    constexpr int H = LANES * 4;
    constexpr int NPB = 256 / LANES;
    int sub = threadIdx.x / LANES;
    int lane = threadIdx.x % LANES;
    int node = blockIdx.x * NPB + sub;
    if (node >= n) return;
    float di = dinv[node];
    float h0[4];
    load4f<unsigned short>(hpre + (size_t)node * H + lane * 4, h0);
    float sw = di * di;  // self-loop norm = 1/deg
    float ax = h0[0] * sw, ay = h0[1] * sw, az = h0[2] * sw, aw = h0[3] * sw;
    int e0 = rowptr[node], e1 = rowptr[node + 1];
    for (int p = e0; p < e1; ++p) {
        int s = csr_src[p];
        float w = dinv[s] * di;
        float hs[4];
        load4f<unsigned short>(hpre + (size_t)s * H + lane * 4, hs);
        ax = fmaf(hs[0], w, ax); ay = fmaf(hs[1], w, ay);
        az = fmaf(hs[2], w, az); aw = fmaf(hs[3], w, aw);
    }
    float4 bv = *(reinterpret_cast<const float4*>(bias) + lane);
    ax += bv.x; ay += bv.y; az += bv.z; aw += bv.w;
    ushort4 o;
    o.x = f2bf(fmaxf(ax, 0.f)); o.y = f2bf(fmaxf(ay, 0.f));
    o.z = f2bf(fmaxf(az, 0.f)); o.w = f2bf(fmaxf(aw, 0.f));
    *(reinterpret_cast<ushort4*>(hout + (size_t)node * H) + lane) = o;
}

// ---------- head: out = log_softmax(h2 @ Wl + bl) ; h2 bf16 [n,128], out fp32 [n,4] ----------
__global__ __launch_bounds__(256) void head_kernel(const unsigned short* __restrict__ h2,
                                                   const float* __restrict__ Wl,
                                                   const float* __restrict__ bl,
                                                   float* __restrict__ out, int n) {
    __shared__ float w[512];
    __shared__ float bs[4];
    if (threadIdx.x < 4) bs[threadIdx.x] = bl[threadIdx.x];
    for (int i = threadIdx.x; i < 512; i += 256) w[i] = Wl[i];
    __syncthreads();
    int node = blockIdx.x * 256 + threadIdx.x;
    if (node >= n) return;
    float a0 = bs[0], a1 = bs[1], a2 = bs[2], a3 = bs[3];
    const unsigned short* hp = h2 + (size_t)node * 128;
    #pragma unroll
    for (int k4 = 0; k4 < 32; ++k4) {
        float h[4];
        load4f<unsigned short>(hp + k4 * 4, h);
        const float* wr = &w[k4 * 16];
        a0 += h[0] * wr[0] + h[1] * wr[4] + h[2] * wr[8]  + h[3] * wr[12];
        a1 += h[0] * wr[1] + h[1] * wr[5] + h[2] * wr[9]  + h[3] * wr[13];
        a2 += h[0] * wr[2] + h[1] * wr[6] + h[2] * wr[10] + h[3] * wr[14];
        a3 += h[0] * wr[3] + h[1] * wr[7] + h[2] * wr[11] + h[3] * wr[15];
    }
    float m = fmaxf(fmaxf(a0, a1), fmaxf(a2, a3));
    float s = __expf(a0 - m) + __expf(a1 - m) + __expf(a2 - m) + __expf(a3 - m);
    float lse = m + __logf(s);
    float4 o = make_float4(a0 - lse, a1 - lse, a2 - lse, a3 - lse);
    *(reinterpret_cast<float4*>(out) + node) = o;
}

// ---------- launch ----------
extern "C" void kernel_launch(void* const* d_in, const int* in_sizes, int n_in,
                              void* d_out, int out_size, void* d_ws, size_t ws_size,
                              hipStream_t stream) {
    const float* x  = (const float*)d_in[0];   // [N,512] f32
    const int* eidx = (const int*)d_in[1];     // [2,E] int32
    const float* W1 = (const float*)d_in[2];   // [512,256] f32
    const float* b1 = (const float*)d_in[3];   // [256]
    const float* W2 = (const float*)d_in[4];   // [256,128]
    const float* b2 = (const float*)d_in[5];   // [128]
    const float* Wl = (const float*)d_in[6];   // [128,4]
    const float* bl = (const float*)d_in[7];   // [4]
    float* out = (float*)d_out;                // [N,4] f32

    const int n = in_sizes[0] / 512;
    const int E = in_sizes[1] / 2;

    char* ws = (char*)d_ws;
    size_t off = 0;
    auto alloc = [&](size_t bytes) -> void* {
        void* p = ws + off;
        off += (bytes + 255) & ~(size_t)255;
        return p;
    };
    unsigned short* hA = (unsigned short*)alloc((size_t)n * 256 * 2);  // pre-agg (bf16)
    unsigned short* hB = (unsigned short*)alloc((size_t)n * 256 * 2);  // post-agg (bf16)
    int* deg     = (int*)alloc((size_t)n * 4);
    int* rowptr  = (int*)alloc(((size_t)n + 1) * 4);
    int* cursor  = (int*)alloc((size_t)n * 4);
    float* dinv  = (float*)alloc((size_t)n * 4);
    int* csr_src = (int*)alloc((size_t)E * 4);

    // CSR build (reused by both layers)
    hipMemsetAsync(deg, 0, (size_t)n * 4, stream);
    hist_kernel<<<dim3(1024), dim3(256), 0, stream>>>(eidx + E, E, deg);
    scan_kernel<<<dim3(1), dim3(256), 0, stream>>>(deg, rowptr, n);
    dinv_kernel<<<dim3((n + 255) / 256), dim3(256), 0, stream>>>(deg, dinv, n);
    hipMemcpyAsync(cursor, rowptr, (size_t)n * 4, hipMemcpyDeviceToDevice, stream);
    fill_kernel<<<dim3((E + 255) / 256), dim3(256), 0, stream>>>(eidx, E, cursor, csr_src);

    // Layer 1: h1 = relu(agg(x@W1) + b1)
    gemm_kernel<float><<<dim3(256 / 64, (n + 63) / 64), dim3(256), 0, stream>>>(
        x, W1, hA, n, 256, 512);
    agg_kernel<64><<<dim3((n + 3) / 4), dim3(256), 0, stream>>>(
        hA, dinv, rowptr, csr_src, b1, hB, n);

    // Layer 2: h2 = relu(agg(h1@W2) + b2)
    gemm_kernel<unsigned short><<<dim3(128 / 64, (n + 63) / 64), dim3(256), 0, stream>>>(
        hB, W2, hA, n, 128, 256);
    agg_kernel<32><<<dim3((n + 7) / 8), dim3(256), 0, stream>>>(
        hA, dinv, rowptr, csr_src, b2, hB, n);

    // Head: log_softmax(h2 @ Wl + bl)
    head_kernel<<<dim3((n + 255) / 256), dim3(256), 0, stream>>>(hB, Wl, bl, out, n);
}

// Round 3
// 1261.007 us; speedup vs baseline: 1.4780x; 1.4780x over previous
//
#include <hip/hip_runtime.h>
#include <hip/hip_bf16.h>
#include <cstdint>
#include <cstddef>

// ---------- helpers ----------
__device__ __forceinline__ float bf2f(unsigned short u) {
    return __uint_as_float(((unsigned int)u) << 16);
}
__device__ __forceinline__ unsigned short f2bf(float f) {
    unsigned int u = __float_as_uint(f);
    unsigned int r = (u + 0x7fff + ((u >> 16) & 1)) >> 16;
    return (unsigned short)r;
}

using bf16x8 = __attribute__((ext_vector_type(8))) short;
using f32x4  = __attribute__((ext_vector_type(4))) float;

// ---------- CSR build ----------
__global__ __launch_bounds__(256) void hist_kernel(const int* __restrict__ dst, int E,
                                                   int* __restrict__ deg) {
    int i = blockIdx.x * blockDim.x + threadIdx.x;
    int stride = gridDim.x * blockDim.x;
    for (int e = i; e < E; e += stride) atomicAdd(&deg[dst[e]], 1);
}

// single-block scan: 256 threads x 16 elems/thread per iteration (4096/iter)
__global__ __launch_bounds__(256) void scan_kernel(const int* __restrict__ deg,
                                                   int* __restrict__ rowptr, int n) {
    __shared__ int wsum[4];
    __shared__ int carry_s;
    int tid = threadIdx.x, lane = tid & 63, wave = tid >> 6;
    if (tid == 0) carry_s = 0;
    __syncthreads();
    const int CHUNK = 16;
    const int PER_ITER = 256 * CHUNK;  // 4096
    for (int base = 0; base < n; base += PER_ITER) {
        int idx0 = base + tid * CHUNK;
        int v[CHUNK];
        int s = 0;
        #pragma unroll
        for (int j = 0; j < CHUNK; ++j) {
            int i = idx0 + j;
            v[j] = (i < n) ? deg[i] : 0;
            s += v[j];
        }
        int inc = s;
        #pragma unroll
        for (int off = 1; off < 64; off <<= 1) {
            int t = __shfl_up(inc, off, 64);
            if (lane >= off) inc += t;
        }
        if (lane == 63) wsum[wave] = inc;
        __syncthreads();
        int wbase = 0;
        #pragma unroll
        for (int w = 0; w < 4; ++w)
            if (w < wave) wbase += wsum[w];
        int total_iter = wsum[0] + wsum[1] + wsum[2] + wsum[3];
        int carry = carry_s;
        __syncthreads();
        if (tid == 0) carry_s = carry + total_iter;
        int run = carry + wbase + (inc - s);
        #pragma unroll
        for (int j = 0; j < CHUNK; ++j) {
            int i = idx0 + j;
            if (i < n) rowptr[i] = run;
            run += v[j];
        }
        __syncthreads();
    }
    if (tid == 0) rowptr[n] = carry_s;
}

__global__ __launch_bounds__(256) void dinv_kernel(const int* __restrict__ deg,
                                                   float* __restrict__ dinv, int n) {
    int i = blockIdx.x * blockDim.x + threadIdx.x;
    if (i < n) dinv[i] = rsqrtf((float)deg[i] + 1.0f);  // +1 self loop
}

__global__ __launch_bounds__(256) void fill_kernel(const int* __restrict__ eidx, int E,
                                                   int* __restrict__ cursor,
                                                   int* __restrict__ csr_src) {
    int e = blockIdx.x * blockDim.x + threadIdx.x;
    if (e < E) {
        int s = eidx[e];
        int d = eidx[E + e];
        int pos = atomicAdd(&cursor[d], 1);
        csr_src[pos] = s;
    }
}

// ---------- weight transpose+convert: W [K,N] f32 -> WT [N,K] bf16 ----------
__global__ __launch_bounds__(256) void wt_kernel(const float* __restrict__ W,
                                                 unsigned short* __restrict__ WT,
                                                 int K, int N) {
    int i = blockIdx.x * 256 + threadIdx.x;
    if (i < K * N) {
        int nn = i / K, kk = i % K;
        WT[i] = f2bf(W[(size_t)kk * N + nn]);
    }
}

// ---------- A-tile LDS staging loaders ----------
__device__ __forceinline__ bf16x8 load8_as_bf16(const float* p) {
    float4 lo = *reinterpret_cast<const float4*>(p);
    float4 hi = *reinterpret_cast<const float4*>(p + 4);
    bf16x8 r;
    r[0] = (short)f2bf(lo.x); r[1] = (short)f2bf(lo.y);
    r[2] = (short)f2bf(lo.z); r[3] = (short)f2bf(lo.w);
    r[4] = (short)f2bf(hi.x); r[5] = (short)f2bf(hi.y);
    r[6] = (short)f2bf(hi.z); r[7] = (short)f2bf(hi.w);
    return r;
}
__device__ __forceinline__ bf16x8 load8_as_bf16(const unsigned short* p) {
    return *reinterpret_cast<const bf16x8*>(p);
}

// ---------- MFMA GEMM: C[M,N](bf16, scaled by dinv[row]) = A[M,K] * BT[N,K]^T ----------
// 64x64 tile, 4 waves; wave w owns rows w*16..w*16+15, 4 col-tiles of 16.
template <typename AT>
__global__ __launch_bounds__(256) void gemm_mfma(const AT* __restrict__ A,
                                                 const unsigned short* __restrict__ BT,
                                                 const float* __restrict__ dinv,
                                                 unsigned short* __restrict__ C,
                                                 int M, int N, int K) {
    constexpr int LP = 40;  // padded LDS row stride (shorts): 80B -> conflict-free b128
    __shared__ short As[64 * LP];
    __shared__ short Bs[64 * LP];
    const int tid = threadIdx.x;
    const int wave = tid >> 6, lane = tid & 63;
    const int quad = lane >> 4, l16 = lane & 15;
    const int m0 = blockIdx.x * 64, n0 = blockIdx.y * 64;
    const int srow = tid >> 2, sseg = (tid & 3) * 8;  // staging: 8 elems/thread
    const int arow = m0 + srow;
    f32x4 acc[4] = {};

    for (int k0 = 0; k0 < K; k0 += 32) {
        bf16x8 av = {};
        if (arow < M) av = load8_as_bf16(A + (size_t)arow * K + k0 + sseg);
        bf16x8 bv = load8_as_bf16(BT + (size_t)(n0 + srow) * K + k0 + sseg);
        *reinterpret_cast<bf16x8*>(&As[srow * LP + sseg]) = av;
        *reinterpret_cast<bf16x8*>(&Bs[srow * LP + sseg]) = bv;
        __syncthreads();
        // A frag: lane holds A[m=l16][k=quad*8+j]
        bf16x8 af = *reinterpret_cast<bf16x8*>(&As[(wave * 16 + l16) * LP + quad * 8]);
        #pragma unroll
        for (int ct = 0; ct < 4; ++ct) {
            // B frag: lane holds B[k=quad*8+j][n=l16] == BT[n][k]
            bf16x8 bfr = *reinterpret_cast<bf16x8*>(&Bs[(ct * 16 + l16) * LP + quad * 8]);
            acc[ct] = __builtin_amdgcn_mfma_f32_16x16x32_bf16(af, bfr, acc[ct], 0, 0, 0);
        }
        __syncthreads();
    }
    // C/D: row = quad*4 + r (within wave strip), col = l16 (within col-tile)
    #pragma unroll
    for (int r = 0; r < 4; ++r) {
        int row = m0 + wave * 16 + quad * 4 + r;
        if (row < M) {
            float dv = dinv[row];
            #pragma unroll
            for (int ct = 0; ct < 4; ++ct) {
                C[(size_t)row * N + n0 + ct * 16 + l16] = f2bf(acc[ct][r] * dv);
            }
        }
    }
}

// ---------- aggregation: out[i] = relu( dinv[i]*(sum_src hs[src] + hs[i]) + bias ) ----------
// hs is the dinv-prescaled table (bf16). LANES lanes/node, 4 feats/lane (H=LANES*4).
template <int LANES>
__global__ __launch_bounds__(256) void agg_kernel(const unsigned short* __restrict__ hs,
                                                  const float* __restrict__ dinv,
                                                  const int* __restrict__ rowptr,
                                                  const int* __restrict__ csr_src,
                                                  const float* __restrict__ bias,
                                                  unsigned short* __restrict__ hout, int n) {
    constexpr int H = LANES * 4;
    constexpr int NPB = 256 / LANES;
    int sub = threadIdx.x / LANES;
    int lane = threadIdx.x % LANES;
    int node = blockIdx.x * NPB + sub;
    if (node >= n) return;
    const unsigned short* tab = hs + (size_t)lane * 4;
    // self contribution
    ushort4 v = *reinterpret_cast<const ushort4*>(tab + (size_t)node * H);
    float a0 = bf2f(v.x), a1 = bf2f(v.y), a2 = bf2f(v.z), a3 = bf2f(v.w);
    int e0 = rowptr[node], e1 = rowptr[node + 1];
    int p = e0;
    // unroll x4: 4 independent gathers in flight per wave
    for (; p + 4 <= e1; p += 4) {
        int s0 = csr_src[p], s1 = csr_src[p + 1], s2 = csr_src[p + 2], s3 = csr_src[p + 3];
        ushort4 v0 = *reinterpret_cast<const ushort4*>(tab + (size_t)s0 * H);
        ushort4 v1 = *reinterpret_cast<const ushort4*>(tab + (size_t)s1 * H);
        ushort4 v2 = *reinterpret_cast<const ushort4*>(tab + (size_t)s2 * H);
        ushort4 v3 = *reinterpret_cast<const ushort4*>(tab + (size_t)s3 * H);
        a0 += bf2f(v0.x) + bf2f(v1.x) + bf2f(v2.x) + bf2f(v3.x);
        a1 += bf2f(v0.y) + bf2f(v1.y) + bf2f(v2.y) + bf2f(v3.y);
        a2 += bf2f(v0.z) + bf2f(v1.z) + bf2f(v2.z) + bf2f(v3.z);
        a3 += bf2f(v0.w) + bf2f(v1.w) + bf2f(v2.w) + bf2f(v3.w);
    }
    for (; p < e1; ++p) {
        int s = csr_src[p];
        ushort4 vv = *reinterpret_cast<const ushort4*>(tab + (size_t)s * H);
        a0 += bf2f(vv.x); a1 += bf2f(vv.y); a2 += bf2f(vv.z); a3 += bf2f(vv.w);
    }
    float dv = dinv[node];
    float4 bv = *(reinterpret_cast<const float4*>(bias) + lane);
    a0 = fmaf(a0, dv, bv.x); a1 = fmaf(a1, dv, bv.y);
    a2 = fmaf(a2, dv, bv.z); a3 = fmaf(a3, dv, bv.w);
    ushort4 o;
    o.x = f2bf(fmaxf(a0, 0.f)); o.y = f2bf(fmaxf(a1, 0.f));
    o.z = f2bf(fmaxf(a2, 0.f)); o.w = f2bf(fmaxf(a3, 0.f));
    *(reinterpret_cast<ushort4*>(hout + (size_t)node * H) + lane) = o;
}

// ---------- head: out = log_softmax(h2 @ Wl + bl) ; h2 bf16 [n,128], out fp32 [n,4] ----------
__global__ __launch_bounds__(256) void head_kernel(const unsigned short* __restrict__ h2,
                                                   const float* __restrict__ Wl,
                                                   const float* __restrict__ bl,
                                                   float* __restrict__ out, int n) {
    __shared__ float w[512];
    __shared__ float bs[4];
    if (threadIdx.x < 4) bs[threadIdx.x] = bl[threadIdx.x];
    for (int i = threadIdx.x; i < 512; i += 256) w[i] = Wl[i];
    __syncthreads();
    int node = blockIdx.x * 256 + threadIdx.x;
    if (node >= n) return;
    float a0 = bs[0], a1 = bs[1], a2 = bs[2], a3 = bs[3];
    const unsigned short* hp = h2 + (size_t)node * 128;
    #pragma unroll
    for (int k4 = 0; k4 < 32; ++k4) {
        ushort4 hv = *reinterpret_cast<const ushort4*>(hp + k4 * 4);
        float h0 = bf2f(hv.x), h1 = bf2f(hv.y), h2v = bf2f(hv.z), h3 = bf2f(hv.w);
        const float* wr = &w[k4 * 16];
        a0 += h0 * wr[0] + h1 * wr[4] + h2v * wr[8]  + h3 * wr[12];
        a1 += h0 * wr[1] + h1 * wr[5] + h2v * wr[9]  + h3 * wr[13];
        a2 += h0 * wr[2] + h1 * wr[6] + h2v * wr[10] + h3 * wr[14];
        a3 += h0 * wr[3] + h1 * wr[7] + h2v * wr[11] + h3 * wr[15];
    }
    float m = fmaxf(fmaxf(a0, a1), fmaxf(a2, a3));
    float s = __expf(a0 - m) + __expf(a1 - m) + __expf(a2 - m) + __expf(a3 - m);
    float lse = m + __logf(s);
    float4 o = make_float4(a0 - lse, a1 - lse, a2 - lse, a3 - lse);
    *(reinterpret_cast<float4*>(out) + node) = o;
}

// ---------- launch ----------
extern "C" void kernel_launch(void* const* d_in, const int* in_sizes, int n_in,
                              void* d_out, int out_size, void* d_ws, size_t ws_size,
                              hipStream_t stream) {
    const float* x  = (const float*)d_in[0];   // [N,512] f32
    const int* eidx = (const int*)d_in[1];     // [2,E] int32
    const float* W1 = (const float*)d_in[2];   // [512,256] f32
    const float* b1 = (const float*)d_in[3];   // [256]
    const float* W2 = (const float*)d_in[4];   // [256,128]
    const float* b2 = (const float*)d_in[5];   // [128]
    const float* Wl = (const float*)d_in[6];   // [128,4]
    const float* bl = (const float*)d_in[7];   // [4]
    float* out = (float*)d_out;                // [N,4] f32

    const int n = in_sizes[0] / 512;
    const int E = in_sizes[1] / 2;

    char* ws = (char*)d_ws;
    size_t off = 0;
    auto alloc = [&](size_t bytes) -> void* {
        void* p = ws + off;
        off += (bytes + 255) & ~(size_t)255;
        return p;
    };
    unsigned short* hA  = (unsigned short*)alloc((size_t)n * 256 * 2);  // pre-agg (bf16)
    unsigned short* hB  = (unsigned short*)alloc((size_t)n * 256 * 2);  // post-agg (bf16)
    unsigned short* W1T = (unsigned short*)alloc((size_t)256 * 512 * 2);
    unsigned short* W2T = (unsigned short*)alloc((size_t)128 * 256 * 2);
    int* deg     = (int*)alloc((size_t)n * 4);
    int* rowptr  = (int*)alloc(((size_t)n + 1) * 4);
    int* cursor  = (int*)alloc((size_t)n * 4);
    float* dinv  = (float*)alloc((size_t)n * 4);
    int* csr_src = (int*)alloc((size_t)E * 4);

    // CSR build (reused by both layers) + dinv (needed by GEMM epilogue)
    hipMemsetAsync(deg, 0, (size_t)n * 4, stream);
    hist_kernel<<<dim3(1024), dim3(256), 0, stream>>>(eidx + E, E, deg);
    scan_kernel<<<dim3(1), dim3(256), 0, stream>>>(deg, rowptr, n);
    dinv_kernel<<<dim3((n + 255) / 256), dim3(256), 0, stream>>>(deg, dinv, n);
    hipMemcpyAsync(cursor, rowptr, (size_t)n * 4, hipMemcpyDeviceToDevice, stream);
    fill_kernel<<<dim3((E + 255) / 256), dim3(256), 0, stream>>>(eidx, E, cursor, csr_src);

    // Weight prep: W1T [256,512] bf16, W2T [128,256] bf16
    wt_kernel<<<dim3((512 * 256 + 255) / 256), dim3(256), 0, stream>>>(W1, W1T, 512, 256);
    wt_kernel<<<dim3((256 * 128 + 255) / 256), dim3(256), 0, stream>>>(W2, W2T, 256, 128);

    const int mblocks = (n + 63) / 64;

    // Layer 1: hs1 = (x@W1)*dinv  -> agg -> h1 = relu(dinv*(sum+self)+b1)
    gemm_mfma<float><<<dim3(mblocks, 4), dim3(256), 0, stream>>>(
        x, W1T, dinv, hA, n, 256, 512);
    agg_kernel<64><<<dim3((n + 3) / 4), dim3(256), 0, stream>>>(
        hA, dinv, rowptr, csr_src, b1, hB, n);

    // Layer 2: hs2 = (h1@W2)*dinv -> agg -> h2 = relu(dinv*(sum+self)+b2)
    gemm_mfma<unsigned short><<<dim3(mblocks, 2), dim3(256), 0, stream>>>(
        hB, W2T, dinv, hA, n, 128, 256);
    agg_kernel<32><<<dim3((n + 7) / 8), dim3(256), 0, stream>>>(
        hA, dinv, rowptr, csr_src, b2, hB, n);

    // Head: log_softmax(h2 @ Wl + bl)
    head_kernel<<<dim3((n + 255) / 256), dim3(256), 0, stream>>>(hB, Wl, bl, out, n);
}

// Round 5
// 973.072 us; speedup vs baseline: 1.9153x; 1.2959x over previous
//
#include <hip/hip_runtime.h>
#include <hip/hip_bf16.h>
#include <cstdint>
#include <cstddef>

// ---------- helpers ----------
__device__ __forceinline__ float bf2f(unsigned short u) {
    return __uint_as_float(((unsigned int)u) << 16);
}
__device__ __forceinline__ unsigned short f2bf(float f) {
    unsigned int u = __float_as_uint(f);
    unsigned int r = (u + 0x7fff + ((u >> 16) & 1)) >> 16;
    return (unsigned short)r;
}

using bf16x8 = __attribute__((ext_vector_type(8))) short;
using f32x4  = __attribute__((ext_vector_type(4))) float;

// ---------- bucketed CSR build ----------
// buckets of 512 nodes (dst>>9). CAP = mean(16384) + 16 sigma.
#define BKT_SHIFT 9
#define BKT_NODES 512
#define BKT_CAP   18432
#define BIN_TILE  4096

__global__ __launch_bounds__(256) void bin_kernel(const int* __restrict__ eidx, int E,
                                                  int nb, int ntiles,
                                                  int* __restrict__ gcur,
                                                  uint2* __restrict__ binned) {
    __shared__ int cnt[256];
    __shared__ int base[256];
    const int tid = threadIdx.x;
    for (int t = blockIdx.x; t < ntiles; t += gridDim.x) {
        cnt[tid] = 0;
        __syncthreads();
        int s[16], d[16];
        unsigned pk[16];  // (b << 16) | rank  (b<256, rank<4096) ; 0xFFFFFFFF = invalid
        #pragma unroll
        for (int j = 0; j < 16; ++j) {
            int e = t * BIN_TILE + j * 256 + tid;
            if (e < E) {
                s[j] = eidx[e];
                d[j] = eidx[E + e];
                int b = d[j] >> BKT_SHIFT;
                int r = atomicAdd(&cnt[b], 1);
                pk[j] = ((unsigned)b << 16) | (unsigned)r;
            } else {
                pk[j] = 0xFFFFFFFFu;
            }
        }
        __syncthreads();
        if (tid < nb) {
            int c = cnt[tid];
            base[tid] = c ? atomicAdd(&gcur[tid], c) : 0;
        }
        __syncthreads();
        #pragma unroll
        for (int j = 0; j < 16; ++j) {
            if (pk[j] != 0xFFFFFFFFu) {
                int b = (int)(pk[j] >> 16);
                int pos = base[b] + (int)(pk[j] & 0xFFFFu);
                if (pos < BKT_CAP)
                    binned[(size_t)b * BKT_CAP + pos] = make_uint2((unsigned)s[j], (unsigned)d[j]);
            }
        }
        __syncthreads();
    }
}

// per-bucket degree histogram -> deg (replaces global atomic hist)
__global__ __launch_bounds__(256) void bhist_kernel(const uint2* __restrict__ binned,
                                                    const int* __restrict__ gcur,
                                                    int* __restrict__ deg, int n) {
    __shared__ int cnt[BKT_NODES];
    int b = blockIdx.x;
    int base_node = b << BKT_SHIFT;
    for (int i = threadIdx.x; i < BKT_NODES; i += 256) cnt[i] = 0;
    __syncthreads();
    int m = min(gcur[b], BKT_CAP);
    const uint2* eb = binned + (size_t)b * BKT_CAP;
    for (int i = threadIdx.x; i < m; i += 256) {
        int idx = (int)eb[i].y - base_node;
        if (idx >= 0 && idx < BKT_NODES) atomicAdd(&cnt[idx], 1);
    }
    __syncthreads();
    for (int i = threadIdx.x; i < BKT_NODES; i += 256) {
        int node = base_node + i;
        if (node < n) deg[node] = cnt[i];
    }
}

// per-bucket local fill: cursors in LDS, csr_src span contiguous & L2-resident
__global__ __launch_bounds__(256) void lfill_kernel(const uint2* __restrict__ binned,
                                                    const int* __restrict__ gcur,
                                                    const int* __restrict__ rowptr,
                                                    int* __restrict__ csr_src, int n) {
    __shared__ int cur[BKT_NODES];
    int b = blockIdx.x;
    int base_node = b << BKT_SHIFT;
    for (int i = threadIdx.x; i < BKT_NODES; i += 256) {
        int node = base_node + i;
        cur[i] = (node < n) ? rowptr[node] : 0;
    }
    __syncthreads();
    int m = min(gcur[b], BKT_CAP);
    const uint2* eb = binned + (size_t)b * BKT_CAP;
    for (int i = threadIdx.x; i < m; i += 256) {
        uint2 p = eb[i];
        int idx = (int)p.y - base_node;
        if (idx >= 0 && idx < BKT_NODES) {
            int pos = atomicAdd(&cur[idx], 1);
            csr_src[pos] = (int)p.x;
        }
    }
}

// ---------- fallback CSR build (if ws too small for binning staging) ----------
__global__ __launch_bounds__(256) void hist_kernel(const int* __restrict__ dst, int E,
                                                   int* __restrict__ deg) {
    int i = blockIdx.x * blockDim.x + threadIdx.x;
    int stride = gridDim.x * blockDim.x;
    for (int e = i; e < E; e += stride) atomicAdd(&deg[dst[e]], 1);
}

__global__ __launch_bounds__(256) void fill_kernel(const int* __restrict__ eidx, int E,
                                                   int* __restrict__ cursor,
                                                   int* __restrict__ csr_src) {
    int e = blockIdx.x * blockDim.x + threadIdx.x;
    if (e < E) {
        int s = eidx[e];
        int d = eidx[E + e];
        int pos = atomicAdd(&cursor[d], 1);
        csr_src[pos] = s;
    }
}

// single-block scan: 256 threads x 16 elems/thread per iteration (4096/iter)
__global__ __launch_bounds__(256) void scan_kernel(const int* __restrict__ deg,
                                                   int* __restrict__ rowptr, int n) {
    __shared__ int wsum[4];
    __shared__ int carry_s;
    int tid = threadIdx.x, lane = tid & 63, wave = tid >> 6;
    if (tid == 0) carry_s = 0;
    __syncthreads();
    const int CHUNK = 16;
    const int PER_ITER = 256 * CHUNK;  // 4096
    for (int base = 0; base < n; base += PER_ITER) {
        int idx0 = base + tid * CHUNK;
        int v[CHUNK];
        int s = 0;
        #pragma unroll
        for (int j = 0; j < CHUNK; ++j) {
            int i = idx0 + j;
            v[j] = (i < n) ? deg[i] : 0;
            s += v[j];
        }
        int inc = s;
        #pragma unroll
        for (int off = 1; off < 64; off <<= 1) {
            int t = __shfl_up(inc, off, 64);
            if (lane >= off) inc += t;
        }
        if (lane == 63) wsum[wave] = inc;
        __syncthreads();
        int wbase = 0;
        #pragma unroll
        for (int w = 0; w < 4; ++w)
            if (w < wave) wbase += wsum[w];
        int total_iter = wsum[0] + wsum[1] + wsum[2] + wsum[3];
        int carry = carry_s;
        __syncthreads();
        if (tid == 0) carry_s = carry + total_iter;
        int run = carry + wbase + (inc - s);
        #pragma unroll
        for (int j = 0; j < CHUNK; ++j) {
            int i = idx0 + j;
            if (i < n) rowptr[i] = run;
            run += v[j];
        }
        __syncthreads();
    }
    if (tid == 0) rowptr[n] = carry_s;
}

__global__ __launch_bounds__(256) void dinv_kernel(const int* __restrict__ deg,
                                                   float* __restrict__ dinv, int n) {
    int i = blockIdx.x * blockDim.x + threadIdx.x;
    if (i < n) dinv[i] = rsqrtf((float)deg[i] + 1.0f);  // +1 self loop
}

// ---------- weight transpose+convert: W [K,N] f32 -> WT [N,K] bf16 ----------
__global__ __launch_bounds__(256) void wt_kernel(const float* __restrict__ W,
                                                 unsigned short* __restrict__ WT,
                                                 int K, int N) {
    int i = blockIdx.x * 256 + threadIdx.x;
    if (i < K * N) {
        int nn = i / K, kk = i % K;
        WT[i] = f2bf(W[(size_t)kk * N + nn]);
    }
}

// ---------- A-tile LDS staging loaders ----------
__device__ __forceinline__ bf16x8 load8_as_bf16(const float* p) {
    float4 lo = *reinterpret_cast<const float4*>(p);
    float4 hi = *reinterpret_cast<const float4*>(p + 4);
    bf16x8 r;
    r[0] = (short)f2bf(lo.x); r[1] = (short)f2bf(lo.y);
    r[2] = (short)f2bf(lo.z); r[3] = (short)f2bf(lo.w);
    r[4] = (short)f2bf(hi.x); r[5] = (short)f2bf(hi.y);
    r[6] = (short)f2bf(hi.z); r[7] = (short)f2bf(hi.w);
    return r;
}
__device__ __forceinline__ bf16x8 load8_as_bf16(const unsigned short* p) {
    return *reinterpret_cast<const bf16x8*>(p);
}

// ---------- MFMA GEMM: C[M,N](bf16, scaled by dinv[row]) = A[M,K] * BT[N,K]^T ----------
template <typename AT>
__global__ __launch_bounds__(256) void gemm_mfma(const AT* __restrict__ A,
                                                 const unsigned short* __restrict__ BT,
                                                 const float* __restrict__ dinv,
                                                 unsigned short* __restrict__ C,
                                                 int M, int N, int K) {
    constexpr int LP = 40;  // padded LDS row stride (shorts)
    __shared__ short As[64 * LP];
    __shared__ short Bs[64 * LP];
    const int tid = threadIdx.x;
    const int wave = tid >> 6, lane = tid & 63;
    const int quad = lane >> 4, l16 = lane & 15;
    const int m0 = blockIdx.x * 64, n0 = blockIdx.y * 64;
    const int srow = tid >> 2, sseg = (tid & 3) * 8;
    const int arow = m0 + srow;
    f32x4 acc[4] = {};

    for (int k0 = 0; k0 < K; k0 += 32) {
        bf16x8 av = {};
        if (arow < M) av = load8_as_bf16(A + (size_t)arow * K + k0 + sseg);
        bf16x8 bv = load8_as_bf16(BT + (size_t)(n0 + srow) * K + k0 + sseg);
        *reinterpret_cast<bf16x8*>(&As[srow * LP + sseg]) = av;
        *reinterpret_cast<bf16x8*>(&Bs[srow * LP + sseg]) = bv;
        __syncthreads();
        bf16x8 af = *reinterpret_cast<bf16x8*>(&As[(wave * 16 + l16) * LP + quad * 8]);
        #pragma unroll
        for (int ct = 0; ct < 4; ++ct) {
            bf16x8 bfr = *reinterpret_cast<bf16x8*>(&Bs[(ct * 16 + l16) * LP + quad * 8]);
            acc[ct] = __builtin_amdgcn_mfma_f32_16x16x32_bf16(af, bfr, acc[ct], 0, 0, 0);
        }
        __syncthreads();
    }
    #pragma unroll
    for (int r = 0; r < 4; ++r) {
        int row = m0 + wave * 16 + quad * 4 + r;
        if (row < M) {
            float dv = dinv[row];
            #pragma unroll
            for (int ct = 0; ct < 4; ++ct) {
                C[(size_t)row * N + n0 + ct * 16 + l16] = f2bf(acc[ct][r] * dv);
            }
        }
    }
}

// ---------- aggregation: out[i] = relu( dinv[i]*(sum_src hs[src] + hs[i]) + bias ) ----------
template <int LANES>
__global__ __launch_bounds__(256) void agg_kernel(const unsigned short* __restrict__ hs,
                                                  const float* __restrict__ dinv,
                                                  const int* __restrict__ rowptr,
                                                  const int* __restrict__ csr_src,
                                                  const float* __restrict__ bias,
                                                  unsigned short* __restrict__ hout, int n) {
    constexpr int H = LANES * 4;
    constexpr int NPB = 256 / LANES;
    int sub = threadIdx.x / LANES;
    int lane = threadIdx.x % LANES;
    int node = blockIdx.x * NPB + sub;
    if (node >= n) return;
    const unsigned short* tab = hs + (size_t)lane * 4;
    ushort4 v = *reinterpret_cast<const ushort4*>(tab + (size_t)node * H);
    float a0 = bf2f(v.x), a1 = bf2f(v.y), a2 = bf2f(v.z), a3 = bf2f(v.w);
    int e0 = rowptr[node], e1 = rowptr[node + 1];
    int p = e0;
    for (; p + 4 <= e1; p += 4) {
        int s0 = csr_src[p], s1 = csr_src[p + 1], s2 = csr_src[p + 2], s3 = csr_src[p + 3];
        ushort4 v0 = *reinterpret_cast<const ushort4*>(tab + (size_t)s0 * H);
        ushort4 v1 = *reinterpret_cast<const ushort4*>(tab + (size_t)s1 * H);
        ushort4 v2 = *reinterpret_cast<const ushort4*>(tab + (size_t)s2 * H);
        ushort4 v3 = *reinterpret_cast<const ushort4*>(tab + (size_t)s3 * H);
        a0 += bf2f(v0.x) + bf2f(v1.x) + bf2f(v2.x) + bf2f(v3.x);
        a1 += bf2f(v0.y) + bf2f(v1.y) + bf2f(v2.y) + bf2f(v3.y);
        a2 += bf2f(v0.z) + bf2f(v1.z) + bf2f(v2.z) + bf2f(v3.z);
        a3 += bf2f(v0.w) + bf2f(v1.w) + bf2f(v2.w) + bf2f(v3.w);
    }
    for (; p < e1; ++p) {
        int s = csr_src[p];
        ushort4 vv = *reinterpret_cast<const ushort4*>(tab + (size_t)s * H);
        a0 += bf2f(vv.x); a1 += bf2f(vv.y); a2 += bf2f(vv.z); a3 += bf2f(vv.w);
    }
    float dv = dinv[node];
    float4 bv = *(reinterpret_cast<const float4*>(bias) + lane);
    a0 = fmaf(a0, dv, bv.x); a1 = fmaf(a1, dv, bv.y);
    a2 = fmaf(a2, dv, bv.z); a3 = fmaf(a3, dv, bv.w);
    ushort4 o;
    o.x = f2bf(fmaxf(a0, 0.f)); o.y = f2bf(fmaxf(a1, 0.f));
    o.z = f2bf(fmaxf(a2, 0.f)); o.w = f2bf(fmaxf(a3, 0.f));
    *(reinterpret_cast<ushort4*>(hout + (size_t)node * H) + lane) = o;
}

// ---------- head ----------
__global__ __launch_bounds__(256) void head_kernel(const unsigned short* __restrict__ h2,
                                                   const float* __restrict__ Wl,
                                                   const float* __restrict__ bl,
                                                   float* __restrict__ out, int n) {
    __shared__ float w[512];
    __shared__ float bs[4];
    if (threadIdx.x < 4) bs[threadIdx.x] = bl[threadIdx.x];
    for (int i = threadIdx.x; i < 512; i += 256) w[i] = Wl[i];
    __syncthreads();
    int node = blockIdx.x * 256 + threadIdx.x;
    if (node >= n) return;
    float a0 = bs[0], a1 = bs[1], a2 = bs[2], a3 = bs[3];
    const unsigned short* hp = h2 + (size_t)node * 128;
    #pragma unroll
    for (int k4 = 0; k4 < 32; ++k4) {
        ushort4 hv = *reinterpret_cast<const ushort4*>(hp + k4 * 4);
        float h0 = bf2f(hv.x), h1 = bf2f(hv.y), h2v = bf2f(hv.z), h3 = bf2f(hv.w);
        const float* wr = &w[k4 * 16];
        a0 += h0 * wr[0] + h1 * wr[4] + h2v * wr[8]  + h3 * wr[12];
        a1 += h0 * wr[1] + h1 * wr[5] + h2v * wr[9]  + h3 * wr[13];
        a2 += h0 * wr[2] + h1 * wr[6] + h2v * wr[10] + h3 * wr[14];
        a3 += h0 * wr[3] + h1 * wr[7] + h2v * wr[11] + h3 * wr[15];
    }
    float m = fmaxf(fmaxf(a0, a1), fmaxf(a2, a3));
    float s = __expf(a0 - m) + __expf(a1 - m) + __expf(a2 - m) + __expf(a3 - m);
    float lse = m + __logf(s);
    float4 o = make_float4(a0 - lse, a1 - lse, a2 - lse, a3 - lse);
    *(reinterpret_cast<float4*>(out) + node) = o;
}

// ---------- launch ----------
extern "C" void kernel_launch(void* const* d_in, const int* in_sizes, int n_in,
                              void* d_out, int out_size, void* d_ws, size_t ws_size,
                              hipStream_t stream) {
    const float* x  = (const float*)d_in[0];
    const int* eidx = (const int*)d_in[1];
    const float* W1 = (const float*)d_in[2];
    const float* b1 = (const float*)d_in[3];
    const float* W2 = (const float*)d_in[4];
    const float* b2 = (const float*)d_in[5];
    const float* Wl = (const float*)d_in[6];
    const float* bl = (const float*)d_in[7];
    float* out = (float*)d_out;

    const int n = in_sizes[0] / 512;
    const int E = in_sizes[1] / 2;
    const int nb = (n + BKT_NODES - 1) >> BKT_SHIFT;  // 196 for n=100000

    char* ws = (char*)d_ws;
    size_t off = 0;
    auto alloc = [&](size_t bytes) -> void* {
        void* p = ws + off;
        off += (bytes + 255) & ~(size_t)255;
        return p;
    };
    unsigned short* hA  = (unsigned short*)alloc((size_t)n * 256 * 2);
    unsigned short* hB  = (unsigned short*)alloc((size_t)n * 256 * 2);
    unsigned short* W1T = (unsigned short*)alloc((size_t)256 * 512 * 2);
    unsigned short* W2T = (unsigned short*)alloc((size_t)128 * 256 * 2);
    int* deg     = (int*)alloc((size_t)n * 4);
    int* rowptr  = (int*)alloc(((size_t)n + 1) * 4);
    int* cursor  = (int*)alloc((size_t)n * 4);
    float* dinv  = (float*)alloc((size_t)n * 4);
    int* csr_src = (int*)alloc((size_t)E * 4);
    int* gcur    = (int*)alloc((size_t)nb * 4);
    size_t need_binned = off + (size_t)nb * BKT_CAP * 8 + 256;
    uint2* binned = (uint2*)alloc((size_t)nb * BKT_CAP * 8);

    if (need_binned <= ws_size && nb <= 256) {
        // bucketed CSR build: line-dense writes, LDS atomics
        hipMemsetAsync(gcur, 0, (size_t)nb * 4, stream);
        int ntiles = (E + BIN_TILE - 1) / BIN_TILE;
        bin_kernel<<<dim3(256), dim3(256), 0, stream>>>(eidx, E, nb, ntiles, gcur, binned);
        bhist_kernel<<<dim3(nb), dim3(256), 0, stream>>>(binned, gcur, deg, n);
        scan_kernel<<<dim3(1), dim3(256), 0, stream>>>(deg, rowptr, n);
        dinv_kernel<<<dim3((n + 255) / 256), dim3(256), 0, stream>>>(deg, dinv, n);
        lfill_kernel<<<dim3(nb), dim3(256), 0, stream>>>(binned, gcur, rowptr, csr_src, n);
    } else {
        // fallback: global-atomic CSR build
        hipMemsetAsync(deg, 0, (size_t)n * 4, stream);
        hist_kernel<<<dim3(1024), dim3(256), 0, stream>>>(eidx + E, E, deg);
        scan_kernel<<<dim3(1), dim3(256), 0, stream>>>(deg, rowptr, n);
        dinv_kernel<<<dim3((n + 255) / 256), dim3(256), 0, stream>>>(deg, dinv, n);
        hipMemcpyAsync(cursor, rowptr, (size_t)n * 4, hipMemcpyDeviceToDevice, stream);
        fill_kernel<<<dim3((E + 255) / 256), dim3(256), 0, stream>>>(eidx, E, cursor, csr_src);
    }

    // Weight prep
    wt_kernel<<<dim3((512 * 256 + 255) / 256), dim3(256), 0, stream>>>(W1, W1T, 512, 256);
    wt_kernel<<<dim3((256 * 128 + 255) / 256), dim3(256), 0, stream>>>(W2, W2T, 256, 128);

    const int mblocks = (n + 63) / 64;

    // Layer 1
    gemm_mfma<float><<<dim3(mblocks, 4), dim3(256), 0, stream>>>(
        x, W1T, dinv, hA, n, 256, 512);
    agg_kernel<64><<<dim3((n + 3) / 4), dim3(256), 0, stream>>>(
        hA, dinv, rowptr, csr_src, b1, hB, n);

    // Layer 2
    gemm_mfma<unsigned short><<<dim3(mblocks, 2), dim3(256), 0, stream>>>(
        hB, W2T, dinv, hA, n, 128, 256);
    agg_kernel<32><<<dim3((n + 7) / 8), dim3(256), 0, stream>>>(
        hA, dinv, rowptr, csr_src, b2, hB, n);

    // Head
    head_kernel<<<dim3((n + 255) / 256), dim3(256), 0, stream>>>(hB, Wl, bl, out, n);
}

// Round 6
// 877.731 us; speedup vs baseline: 2.1234x; 1.1086x over previous
//
#include <hip/hip_runtime.h>
#include <hip/hip_bf16.h>
#include <cstdint>
#include <cstddef>

// ---------- helpers ----------
__device__ __forceinline__ float bf2f(unsigned short u) {
    return __uint_as_float(((unsigned int)u) << 16);
}
__device__ __forceinline__ unsigned short f2bf(float f) {
    unsigned int u = __float_as_uint(f);
    unsigned int r = (u + 0x7fff + ((u >> 16) & 1)) >> 16;
    return (unsigned short)r;
}

using bf16x8 = __attribute__((ext_vector_type(8))) short;
using f32x4  = __attribute__((ext_vector_type(4))) float;

// ---------- bucketed CSR build ----------
// buckets of 512 nodes (dst>>9). CAP = mean(16384) + 16 sigma.
#define BKT_SHIFT 9
#define BKT_NODES 512
#define BKT_CAP   18432
#define BIN_TILE  4096

__global__ __launch_bounds__(256) void bin_kernel(const int* __restrict__ eidx, int E,
                                                  int nb, int ntiles,
                                                  int* __restrict__ gcur,
                                                  uint2* __restrict__ binned) {
    __shared__ int cnt[256];
    __shared__ int base[256];
    const int tid = threadIdx.x;
    for (int t = blockIdx.x; t < ntiles; t += gridDim.x) {
        cnt[tid] = 0;
        __syncthreads();
        int s[16], d[16];
        unsigned pk[16];  // (b << 16) | rank ; 0xFFFFFFFF = invalid
        #pragma unroll
        for (int j = 0; j < 16; ++j) {
            int e = t * BIN_TILE + j * 256 + tid;
            if (e < E) {
                s[j] = eidx[e];
                d[j] = eidx[E + e];
                int b = d[j] >> BKT_SHIFT;
                int r = atomicAdd(&cnt[b], 1);
                pk[j] = ((unsigned)b << 16) | (unsigned)r;
            } else {
                pk[j] = 0xFFFFFFFFu;
            }
        }
        __syncthreads();
        if (tid < nb) {
            int c = cnt[tid];
            base[tid] = c ? atomicAdd(&gcur[tid], c) : 0;
        }
        __syncthreads();
        #pragma unroll
        for (int j = 0; j < 16; ++j) {
            if (pk[j] != 0xFFFFFFFFu) {
                int b = (int)(pk[j] >> 16);
                int pos = base[b] + (int)(pk[j] & 0xFFFFu);
                if (pos < BKT_CAP)
                    binned[(size_t)b * BKT_CAP + pos] = make_uint2((unsigned)s[j], (unsigned)d[j]);
            }
        }
        __syncthreads();
    }
}

// scan per-bucket totals -> gbase (exclusive); writes rowptr[n]. single block, nb<=256.
__global__ __launch_bounds__(256) void bucket_scan_kernel(const int* __restrict__ gcur,
                                                          int* __restrict__ gbase,
                                                          int* __restrict__ rowptr, int nb, int n) {
    __shared__ int wsum[4];
    int tid = threadIdx.x, lane = tid & 63, wave = tid >> 6;
    int c = (tid < nb) ? min(gcur[tid], BKT_CAP) : 0;
    int inc = c;
    #pragma unroll
    for (int off = 1; off < 64; off <<= 1) {
        int t = __shfl_up(inc, off, 64);
        if (lane >= off) inc += t;
    }
    if (lane == 63) wsum[wave] = inc;
    __syncthreads();
    int wbase = 0;
    #pragma unroll
    for (int w = 0; w < 4; ++w)
        if (w < wave) wbase += wsum[w];
    int excl = wbase + inc - c;
    if (tid < nb) gbase[tid] = excl;
    if (tid == nb - 1) rowptr[n] = excl + c;
}

// per-bucket: histogram + local prefix scan -> rowptr, dinv (replaces global scan+hist)
__global__ __launch_bounds__(256) void bhist_scan_kernel(const uint2* __restrict__ binned,
                                                         const int* __restrict__ gcur,
                                                         const int* __restrict__ gbase,
                                                         int* __restrict__ rowptr,
                                                         float* __restrict__ dinv, int n) {
    __shared__ int cnt[BKT_NODES];
    __shared__ int wsum[4];
    int b = blockIdx.x;
    int base_node = b << BKT_SHIFT;
    int tid = threadIdx.x, lane = tid & 63, wave = tid >> 6;
    for (int i = tid; i < BKT_NODES; i += 256) cnt[i] = 0;
    __syncthreads();
    int m = min(gcur[b], BKT_CAP);
    const uint2* eb = binned + (size_t)b * BKT_CAP;
    for (int i = tid; i < m; i += 256) {
        int idx = (int)eb[i].y - base_node;
        if (idx >= 0 && idx < BKT_NODES) atomicAdd(&cnt[idx], 1);
    }
    __syncthreads();
    // scan 512 counts: thread t owns elems 2t, 2t+1
    int c0 = cnt[2 * tid], c1 = cnt[2 * tid + 1];
    int s = c0 + c1;
    int inc = s;
    #pragma unroll
    for (int off = 1; off < 64; off <<= 1) {
        int t = __shfl_up(inc, off, 64);
        if (lane >= off) inc += t;
    }
    if (lane == 63) wsum[wave] = inc;
    __syncthreads();
    int wbase = 0;
    #pragma unroll
    for (int w = 0; w < 4; ++w)
        if (w < wave) wbase += wsum[w];
    int excl = wbase + inc - s;  // exclusive prefix for elem 2t
    int gb = gbase[b];
    int node0 = base_node + 2 * tid;
    if (node0 < n) {
        rowptr[node0] = gb + excl;
        dinv[node0] = rsqrtf((float)c0 + 1.0f);
    }
    if (node0 + 1 < n) {
        rowptr[node0 + 1] = gb + excl + c0;
        dinv[node0 + 1] = rsqrtf((float)c1 + 1.0f);
    }
}

// per-bucket local fill: cursors in LDS, csr_src span contiguous & L2-resident
__global__ __launch_bounds__(256) void lfill_kernel(const uint2* __restrict__ binned,
                                                    const int* __restrict__ gcur,
                                                    const int* __restrict__ rowptr,
                                                    int* __restrict__ csr_src, int n) {
    __shared__ int cur[BKT_NODES];
    int b = blockIdx.x;
    int base_node = b << BKT_SHIFT;
    for (int i = threadIdx.x; i < BKT_NODES; i += 256) {
        int node = base_node + i;
        cur[i] = (node < n) ? rowptr[node] : 0;
    }
    __syncthreads();
    int m = min(gcur[b], BKT_CAP);
    const uint2* eb = binned + (size_t)b * BKT_CAP;
    for (int i = threadIdx.x; i < m; i += 256) {
        uint2 p = eb[i];
        int idx = (int)p.y - base_node;
        if (idx >= 0 && idx < BKT_NODES) {
            int pos = atomicAdd(&cur[idx], 1);
            csr_src[pos] = (int)p.x;
        }
    }
}

// ---------- fallback CSR build (if ws too small for binning staging) ----------
__global__ __launch_bounds__(256) void hist_kernel(const int* __restrict__ dst, int E,
                                                   int* __restrict__ deg) {
    int i = blockIdx.x * blockDim.x + threadIdx.x;
    int stride = gridDim.x * blockDim.x;
    for (int e = i; e < E; e += stride) atomicAdd(&deg[dst[e]], 1);
}

__global__ __launch_bounds__(256) void fill_kernel(const int* __restrict__ eidx, int E,
                                                   int* __restrict__ cursor,
                                                   int* __restrict__ csr_src) {
    int e = blockIdx.x * blockDim.x + threadIdx.x;
    if (e < E) {
        int s = eidx[e];
        int d = eidx[E + e];
        int pos = atomicAdd(&cursor[d], 1);
        csr_src[pos] = s;
    }
}

__global__ __launch_bounds__(256) void scan_kernel(const int* __restrict__ deg,
                                                   int* __restrict__ rowptr, int n) {
    __shared__ int wsum[4];
    __shared__ int carry_s;
    int tid = threadIdx.x, lane = tid & 63, wave = tid >> 6;
    if (tid == 0) carry_s = 0;
    __syncthreads();
    const int CHUNK = 16;
    const int PER_ITER = 256 * CHUNK;
    for (int base = 0; base < n; base += PER_ITER) {
        int idx0 = base + tid * CHUNK;
        int v[CHUNK];
        int s = 0;
        #pragma unroll
        for (int j = 0; j < CHUNK; ++j) {
            int i = idx0 + j;
            v[j] = (i < n) ? deg[i] : 0;
            s += v[j];
        }
        int inc = s;
        #pragma unroll
        for (int off = 1; off < 64; off <<= 1) {
            int t = __shfl_up(inc, off, 64);
            if (lane >= off) inc += t;
        }
        if (lane == 63) wsum[wave] = inc;
        __syncthreads();
        int wbase = 0;
        #pragma unroll
        for (int w = 0; w < 4; ++w)
            if (w < wave) wbase += wsum[w];
        int total_iter = wsum[0] + wsum[1] + wsum[2] + wsum[3];
        int carry = carry_s;
        __syncthreads();
        if (tid == 0) carry_s = carry + total_iter;
        int run = carry + wbase + (inc - s);
        #pragma unroll
        for (int j = 0; j < CHUNK; ++j) {
            int i = idx0 + j;
            if (i < n) rowptr[i] = run;
            run += v[j];
        }
        __syncthreads();
    }
    if (tid == 0) rowptr[n] = carry_s;
}

__global__ __launch_bounds__(256) void dinv_kernel(const int* __restrict__ deg,
                                                   float* __restrict__ dinv, int n) {
    int i = blockIdx.x * blockDim.x + threadIdx.x;
    if (i < n) dinv[i] = rsqrtf((float)deg[i] + 1.0f);
}

// ---------- weight transpose+convert: W [K,N] f32 -> WT [N,K] bf16 ----------
__global__ __launch_bounds__(256) void wt_kernel(const float* __restrict__ W,
                                                 unsigned short* __restrict__ WT,
                                                 int K, int N) {
    int i = blockIdx.x * 256 + threadIdx.x;
    if (i < K * N) {
        int nn = i / K, kk = i % K;
        WT[i] = f2bf(W[(size_t)kk * N + nn]);
    }
}

// ---------- A-tile LDS staging loaders ----------
__device__ __forceinline__ bf16x8 load8_as_bf16(const float* p) {
    float4 lo = *reinterpret_cast<const float4*>(p);
    float4 hi = *reinterpret_cast<const float4*>(p + 4);
    bf16x8 r;
    r[0] = (short)f2bf(lo.x); r[1] = (short)f2bf(lo.y);
    r[2] = (short)f2bf(lo.z); r[3] = (short)f2bf(lo.w);
    r[4] = (short)f2bf(hi.x); r[5] = (short)f2bf(hi.y);
    r[6] = (short)f2bf(hi.z); r[7] = (short)f2bf(hi.w);
    return r;
}
__device__ __forceinline__ bf16x8 load8_as_bf16(const unsigned short* p) {
    return *reinterpret_cast<const bf16x8*>(p);
}

// ---------- MFMA GEMM: C[M,N](bf16, scaled by dinv[row]) = A[M,K] * BT[N,K]^T ----------
template <typename AT>
__global__ __launch_bounds__(256) void gemm_mfma(const AT* __restrict__ A,
                                                 const unsigned short* __restrict__ BT,
                                                 const float* __restrict__ dinv,
                                                 unsigned short* __restrict__ C,
                                                 int M, int N, int K) {
    constexpr int LP = 40;  // padded LDS row stride (shorts)
    __shared__ short As[64 * LP];
    __shared__ short Bs[64 * LP];
    const int tid = threadIdx.x;
    const int wave = tid >> 6, lane = tid & 63;
    const int quad = lane >> 4, l16 = lane & 15;
    const int m0 = blockIdx.x * 64, n0 = blockIdx.y * 64;
    const int srow = tid >> 2, sseg = (tid & 3) * 8;
    const int arow = m0 + srow;
    f32x4 acc[4] = {};

    for (int k0 = 0; k0 < K; k0 += 32) {
        bf16x8 av = {};
        if (arow < M) av = load8_as_bf16(A + (size_t)arow * K + k0 + sseg);
        bf16x8 bv = load8_as_bf16(BT + (size_t)(n0 + srow) * K + k0 + sseg);
        *reinterpret_cast<bf16x8*>(&As[srow * LP + sseg]) = av;
        *reinterpret_cast<bf16x8*>(&Bs[srow * LP + sseg]) = bv;
        __syncthreads();
        bf16x8 af = *reinterpret_cast<bf16x8*>(&As[(wave * 16 + l16) * LP + quad * 8]);
        #pragma unroll
        for (int ct = 0; ct < 4; ++ct) {
            bf16x8 bfr = *reinterpret_cast<bf16x8*>(&Bs[(ct * 16 + l16) * LP + quad * 8]);
            acc[ct] = __builtin_amdgcn_mfma_f32_16x16x32_bf16(af, bfr, acc[ct], 0, 0, 0);
        }
        __syncthreads();
    }
    #pragma unroll
    for (int r = 0; r < 4; ++r) {
        int row = m0 + wave * 16 + quad * 4 + r;
        if (row < M) {
            float dv = dinv[row];
            #pragma unroll
            for (int ct = 0; ct < 4; ++ct) {
                C[(size_t)row * N + n0 + ct * 16 + l16] = f2bf(acc[ct][r] * dv);
            }
        }
    }
}

// ---------- aggregation: out[i] = relu( dinv[i]*(sum_src hs[src] + hs[i]) + bias ) ----------
// 8 feats/lane (16B loads), LANES lanes/node (H = LANES*8), edge loop unrolled x8.
template <int LANES>
__global__ __launch_bounds__(256) void agg_kernel(const unsigned short* __restrict__ hs,
                                                  const float* __restrict__ dinv,
                                                  const int* __restrict__ rowptr,
                                                  const int* __restrict__ csr_src,
                                                  const float* __restrict__ bias,
                                                  unsigned short* __restrict__ hout, int n) {
    constexpr int H = LANES * 8;
    constexpr int NPB = 256 / LANES;
    int sub = threadIdx.x / LANES;
    int lane = threadIdx.x % LANES;
    int node = blockIdx.x * NPB + sub;
    if (node >= n) return;
    const unsigned short* tab = hs + (size_t)lane * 8;
    float a[8];
    bf16x8 v0 = *reinterpret_cast<const bf16x8*>(tab + (size_t)node * H);
    #pragma unroll
    for (int j = 0; j < 8; ++j) a[j] = bf2f((unsigned short)v0[j]);
    int e0 = rowptr[node], e1 = rowptr[node + 1];
    int p = e0;
    for (; p + 8 <= e1; p += 8) {
        int s[8];
        #pragma unroll
        for (int u = 0; u < 8; ++u) s[u] = csr_src[p + u];
        bf16x8 w[8];
        #pragma unroll
        for (int u = 0; u < 8; ++u)
            w[u] = *reinterpret_cast<const bf16x8*>(tab + (size_t)s[u] * H);
        #pragma unroll
        for (int u = 0; u < 8; ++u)
            #pragma unroll
            for (int j = 0; j < 8; ++j) a[j] += bf2f((unsigned short)w[u][j]);
    }
    for (; p < e1; ++p) {
        int s = csr_src[p];
        bf16x8 w = *reinterpret_cast<const bf16x8*>(tab + (size_t)s * H);
        #pragma unroll
        for (int j = 0; j < 8; ++j) a[j] += bf2f((unsigned short)w[j]);
    }
    float dv = dinv[node];
    float4 blo = *(reinterpret_cast<const float4*>(bias) + lane * 2);
    float4 bhi = *(reinterpret_cast<const float4*>(bias) + lane * 2 + 1);
    float bvals[8] = {blo.x, blo.y, blo.z, blo.w, bhi.x, bhi.y, bhi.z, bhi.w};
    bf16x8 o;
    #pragma unroll
    for (int j = 0; j < 8; ++j)
        o[j] = (short)f2bf(fmaxf(fmaf(a[j], dv, bvals[j]), 0.f));
    *reinterpret_cast<bf16x8*>(hout + (size_t)node * H + lane * 8) = o;
}

// ---------- head ----------
__global__ __launch_bounds__(256) void head_kernel(const unsigned short* __restrict__ h2,
                                                   const float* __restrict__ Wl,
                                                   const float* __restrict__ bl,
                                                   float* __restrict__ out, int n) {
    __shared__ float w[512];
    __shared__ float bs[4];
    if (threadIdx.x < 4) bs[threadIdx.x] = bl[threadIdx.x];
    for (int i = threadIdx.x; i < 512; i += 256) w[i] = Wl[i];
    __syncthreads();
    int node = blockIdx.x * 256 + threadIdx.x;
    if (node >= n) return;
    float a0 = bs[0], a1 = bs[1], a2 = bs[2], a3 = bs[3];
    const unsigned short* hp = h2 + (size_t)node * 128;
    #pragma unroll
    for (int k4 = 0; k4 < 32; ++k4) {
        ushort4 hv = *reinterpret_cast<const ushort4*>(hp + k4 * 4);
        float h0 = bf2f(hv.x), h1 = bf2f(hv.y), h2v = bf2f(hv.z), h3 = bf2f(hv.w);
        const float* wr = &w[k4 * 16];
        a0 += h0 * wr[0] + h1 * wr[4] + h2v * wr[8]  + h3 * wr[12];
        a1 += h0 * wr[1] + h1 * wr[5] + h2v * wr[9]  + h3 * wr[13];
        a2 += h0 * wr[2] + h1 * wr[6] + h2v * wr[10] + h3 * wr[14];
        a3 += h0 * wr[3] + h1 * wr[7] + h2v * wr[11] + h3 * wr[15];
    }
    float m = fmaxf(fmaxf(a0, a1), fmaxf(a2, a3));
    float s = __expf(a0 - m) + __expf(a1 - m) + __expf(a2 - m) + __expf(a3 - m);
    float lse = m + __logf(s);
    float4 o = make_float4(a0 - lse, a1 - lse, a2 - lse, a3 - lse);
    *(reinterpret_cast<float4*>(out) + node) = o;
}

// ---------- launch ----------
extern "C" void kernel_launch(void* const* d_in, const int* in_sizes, int n_in,
                              void* d_out, int out_size, void* d_ws, size_t ws_size,
                              hipStream_t stream) {
    const float* x  = (const float*)d_in[0];
    const int* eidx = (const int*)d_in[1];
    const float* W1 = (const float*)d_in[2];
    const float* b1 = (const float*)d_in[3];
    const float* W2 = (const float*)d_in[4];
    const float* b2 = (const float*)d_in[5];
    const float* Wl = (const float*)d_in[6];
    const float* bl = (const float*)d_in[7];
    float* out = (float*)d_out;

    const int n = in_sizes[0] / 512;
    const int E = in_sizes[1] / 2;
    const int nb = (n + BKT_NODES - 1) >> BKT_SHIFT;  // 196 for n=100000

    char* ws = (char*)d_ws;
    size_t off = 0;
    auto alloc = [&](size_t bytes) -> void* {
        void* p = ws + off;
        off += (bytes + 255) & ~(size_t)255;
        return p;
    };
    unsigned short* hA  = (unsigned short*)alloc((size_t)n * 256 * 2);
    unsigned short* hB  = (unsigned short*)alloc((size_t)n * 256 * 2);
    unsigned short* W1T = (unsigned short*)alloc((size_t)256 * 512 * 2);
    unsigned short* W2T = (unsigned short*)alloc((size_t)128 * 256 * 2);
    int* deg     = (int*)alloc((size_t)n * 4);
    int* rowptr  = (int*)alloc(((size_t)n + 1) * 4);
    int* cursor  = (int*)alloc((size_t)n * 4);
    float* dinv  = (float*)alloc((size_t)n * 4);
    int* csr_src = (int*)alloc((size_t)E * 4);
    int* gcur    = (int*)alloc((size_t)nb * 4);
    int* gbase   = (int*)alloc((size_t)nb * 4);
    size_t need_binned = off + (size_t)nb * BKT_CAP * 8 + 256;
    uint2* binned = (uint2*)alloc((size_t)nb * BKT_CAP * 8);

    if (need_binned <= ws_size && nb <= 256) {
        // bucketed CSR build: line-dense writes, LDS atomics, parallel scans
        hipMemsetAsync(gcur, 0, (size_t)nb * 4, stream);
        int ntiles = (E + BIN_TILE - 1) / BIN_TILE;
        bin_kernel<<<dim3(256), dim3(256), 0, stream>>>(eidx, E, nb, ntiles, gcur, binned);
        bucket_scan_kernel<<<dim3(1), dim3(256), 0, stream>>>(gcur, gbase, rowptr, nb, n);
        bhist_scan_kernel<<<dim3(nb), dim3(256), 0, stream>>>(binned, gcur, gbase, rowptr, dinv, n);
        lfill_kernel<<<dim3(nb), dim3(256), 0, stream>>>(binned, gcur, rowptr, csr_src, n);
    } else {
        // fallback: global-atomic CSR build
        hipMemsetAsync(deg, 0, (size_t)n * 4, stream);
        hist_kernel<<<dim3(1024), dim3(256), 0, stream>>>(eidx + E, E, deg);
        scan_kernel<<<dim3(1), dim3(256), 0, stream>>>(deg, rowptr, n);
        dinv_kernel<<<dim3((n + 255) / 256), dim3(256), 0, stream>>>(deg, dinv, n);
        hipMemcpyAsync(cursor, rowptr, (size_t)n * 4, hipMemcpyDeviceToDevice, stream);
        fill_kernel<<<dim3((E + 255) / 256), dim3(256), 0, stream>>>(eidx, E, cursor, csr_src);
    }

    // Weight prep
    wt_kernel<<<dim3((512 * 256 + 255) / 256), dim3(256), 0, stream>>>(W1, W1T, 512, 256);
    wt_kernel<<<dim3((256 * 128 + 255) / 256), dim3(256), 0, stream>>>(W2, W2T, 256, 128);

    const int mblocks = (n + 63) / 64;

    // Layer 1: hs1 = (x@W1)*dinv -> agg (H=256: 32 lanes x 8 feats)
    gemm_mfma<float><<<dim3(mblocks, 4), dim3(256), 0, stream>>>(
        x, W1T, dinv, hA, n, 256, 512);
    agg_kernel<32><<<dim3((n + 7) / 8), dim3(256), 0, stream>>>(
        hA, dinv, rowptr, csr_src, b1, hB, n);

    // Layer 2: hs2 = (h1@W2)*dinv -> agg (H=128: 16 lanes x 8 feats)
    gemm_mfma<unsigned short><<<dim3(mblocks, 2), dim3(256), 0, stream>>>(
        hB, W2T, dinv, hA, n, 128, 256);
    agg_kernel<16><<<dim3((n + 15) / 16), dim3(256), 0, stream>>>(
        hA, dinv, rowptr, csr_src, b2, hB, n);

    // Head: log_softmax(h2 @ Wl + bl)
    head_kernel<<<dim3((n + 255) / 256), dim3(256), 0, stream>>>(hB, Wl, bl, out, n);
}

// Round 7
// 844.341 us; speedup vs baseline: 2.2073x; 1.0395x over previous
//
#include <hip/hip_runtime.h>
#include <hip/hip_bf16.h>
#include <cstdint>
#include <cstddef>

// ---------- helpers ----------
__device__ __forceinline__ float bf2f(unsigned short u) {
    return __uint_as_float(((unsigned int)u) << 16);
}
__device__ __forceinline__ unsigned short f2bf(float f) {
    unsigned int u = __float_as_uint(f);
    unsigned int r = (u + 0x7fff + ((u >> 16) & 1)) >> 16;
    return (unsigned short)r;
}

using bf16x8 = __attribute__((ext_vector_type(8))) short;
using f32x4  = __attribute__((ext_vector_type(4))) float;

// ---------- bucketed CSR build ----------
#define BKT_SHIFT 9
#define BKT_NODES 512
#define BKT_CAP   18432
#define BIN_TILE  4096

__global__ __launch_bounds__(256) void bin_kernel(const int* __restrict__ eidx, int E,
                                                  int nb, int ntiles,
                                                  int* __restrict__ gcur,
                                                  uint2* __restrict__ binned) {
    __shared__ int cnt[256];
    __shared__ int base[256];
    const int tid = threadIdx.x;
    for (int t = blockIdx.x; t < ntiles; t += gridDim.x) {
        cnt[tid] = 0;
        __syncthreads();
        int s[16], d[16];
        unsigned pk[16];  // (b << 16) | rank ; 0xFFFFFFFF = invalid
        #pragma unroll
        for (int j = 0; j < 16; ++j) {
            int e = t * BIN_TILE + j * 256 + tid;
            if (e < E) {
                s[j] = eidx[e];
                d[j] = eidx[E + e];
                int b = d[j] >> BKT_SHIFT;
                int r = atomicAdd(&cnt[b], 1);
                pk[j] = ((unsigned)b << 16) | (unsigned)r;
            } else {
                pk[j] = 0xFFFFFFFFu;
            }
        }
        __syncthreads();
        if (tid < nb) {
            int c = cnt[tid];
            base[tid] = c ? atomicAdd(&gcur[tid], c) : 0;
        }
        __syncthreads();
        #pragma unroll
        for (int j = 0; j < 16; ++j) {
            if (pk[j] != 0xFFFFFFFFu) {
                int b = (int)(pk[j] >> 16);
                int pos = base[b] + (int)(pk[j] & 0xFFFFu);
                if (pos < BKT_CAP)
                    binned[(size_t)b * BKT_CAP + pos] = make_uint2((unsigned)s[j], (unsigned)d[j]);
            }
        }
        __syncthreads();
    }
}

// scan per-bucket totals -> gbase (exclusive); writes rowptr[n]. single block, nb<=256.
__global__ __launch_bounds__(256) void bucket_scan_kernel(const int* __restrict__ gcur,
                                                          int* __restrict__ gbase,
                                                          int* __restrict__ rowptr, int nb, int n) {
    __shared__ int wsum[4];
    int tid = threadIdx.x, lane = tid & 63, wave = tid >> 6;
    int c = (tid < nb) ? min(gcur[tid], BKT_CAP) : 0;
    int inc = c;
    #pragma unroll
    for (int off = 1; off < 64; off <<= 1) {
        int t = __shfl_up(inc, off, 64);
        if (lane >= off) inc += t;
    }
    if (lane == 63) wsum[wave] = inc;
    __syncthreads();
    int wbase = 0;
    #pragma unroll
    for (int w = 0; w < 4; ++w)
        if (w < wave) wbase += wsum[w];
    int excl = wbase + inc - c;
    if (tid < nb) gbase[tid] = excl;
    if (tid == nb - 1) rowptr[n] = excl + c;
}

// per-bucket: histogram + local prefix scan -> rowptr, dinv
__global__ __launch_bounds__(256) void bhist_scan_kernel(const uint2* __restrict__ binned,
                                                         const int* __restrict__ gcur,
                                                         const int* __restrict__ gbase,
                                                         int* __restrict__ rowptr,
                                                         float* __restrict__ dinv, int n) {
    __shared__ int cnt[BKT_NODES];
    __shared__ int wsum[4];
    int b = blockIdx.x;
    int base_node = b << BKT_SHIFT;
    int tid = threadIdx.x, lane = tid & 63, wave = tid >> 6;
    for (int i = tid; i < BKT_NODES; i += 256) cnt[i] = 0;
    __syncthreads();
    int m = min(gcur[b], BKT_CAP);
    const uint2* eb = binned + (size_t)b * BKT_CAP;
    for (int i = tid; i < m; i += 256) {
        int idx = (int)eb[i].y - base_node;
        if (idx >= 0 && idx < BKT_NODES) atomicAdd(&cnt[idx], 1);
    }
    __syncthreads();
    int c0 = cnt[2 * tid], c1 = cnt[2 * tid + 1];
    int s = c0 + c1;
    int inc = s;
    #pragma unroll
    for (int off = 1; off < 64; off <<= 1) {
        int t = __shfl_up(inc, off, 64);
        if (lane >= off) inc += t;
    }
    if (lane == 63) wsum[wave] = inc;
    __syncthreads();
    int wbase = 0;
    #pragma unroll
    for (int w = 0; w < 4; ++w)
        if (w < wave) wbase += wsum[w];
    int excl = wbase + inc - s;
    int gb = gbase[b];
    int node0 = base_node + 2 * tid;
    if (node0 < n) {
        rowptr[node0] = gb + excl;
        dinv[node0] = rsqrtf((float)c0 + 1.0f);
    }
    if (node0 + 1 < n) {
        rowptr[node0 + 1] = gb + excl + c0;
        dinv[node0 + 1] = rsqrtf((float)c1 + 1.0f);
    }
}

// per-bucket local fill
__global__ __launch_bounds__(256) void lfill_kernel(const uint2* __restrict__ binned,
                                                    const int* __restrict__ gcur,
                                                    const int* __restrict__ rowptr,
                                                    int* __restrict__ csr_src, int n) {
    __shared__ int cur[BKT_NODES];
    int b = blockIdx.x;
    int base_node = b << BKT_SHIFT;
    for (int i = threadIdx.x; i < BKT_NODES; i += 256) {
        int node = base_node + i;
        cur[i] = (node < n) ? rowptr[node] : 0;
    }
    __syncthreads();
    int m = min(gcur[b], BKT_CAP);
    const uint2* eb = binned + (size_t)b * BKT_CAP;
    for (int i = threadIdx.x; i < m; i += 256) {
        uint2 p = eb[i];
        int idx = (int)p.y - base_node;
        if (idx >= 0 && idx < BKT_NODES) {
            int pos = atomicAdd(&cur[idx], 1);
            csr_src[pos] = (int)p.x;
        }
    }
}

// ---------- fallback CSR build ----------
__global__ __launch_bounds__(256) void hist_kernel(const int* __restrict__ dst, int E,
                                                   int* __restrict__ deg) {
    int i = blockIdx.x * blockDim.x + threadIdx.x;
    int stride = gridDim.x * blockDim.x;
    for (int e = i; e < E; e += stride) atomicAdd(&deg[dst[e]], 1);
}

__global__ __launch_bounds__(256) void fill_kernel(const int* __restrict__ eidx, int E,
                                                   int* __restrict__ cursor,
                                                   int* __restrict__ csr_src) {
    int e = blockIdx.x * blockDim.x + threadIdx.x;
    if (e < E) {
        int s = eidx[e];
        int d = eidx[E + e];
        int pos = atomicAdd(&cursor[d], 1);
        csr_src[pos] = s;
    }
}

__global__ __launch_bounds__(256) void scan_kernel(const int* __restrict__ deg,
                                                   int* __restrict__ rowptr, int n) {
    __shared__ int wsum[4];
    __shared__ int carry_s;
    int tid = threadIdx.x, lane = tid & 63, wave = tid >> 6;
    if (tid == 0) carry_s = 0;
    __syncthreads();
    const int CHUNK = 16;
    const int PER_ITER = 256 * CHUNK;
    for (int base = 0; base < n; base += PER_ITER) {
        int idx0 = base + tid * CHUNK;
        int v[CHUNK];
        int s = 0;
        #pragma unroll
        for (int j = 0; j < CHUNK; ++j) {
            int i = idx0 + j;
            v[j] = (i < n) ? deg[i] : 0;
            s += v[j];
        }
        int inc = s;
        #pragma unroll
        for (int off = 1; off < 64; off <<= 1) {
            int t = __shfl_up(inc, off, 64);
            if (lane >= off) inc += t;
        }
        if (lane == 63) wsum[wave] = inc;
        __syncthreads();
        int wbase = 0;
        #pragma unroll
        for (int w = 0; w < 4; ++w)
            if (w < wave) wbase += wsum[w];
        int total_iter = wsum[0] + wsum[1] + wsum[2] + wsum[3];
        int carry = carry_s;
        __syncthreads();
        if (tid == 0) carry_s = carry + total_iter;
        int run = carry + wbase + (inc - s);
        #pragma unroll
        for (int j = 0; j < CHUNK; ++j) {
            int i = idx0 + j;
            if (i < n) rowptr[i] = run;
            run += v[j];
        }
        __syncthreads();
    }
    if (tid == 0) rowptr[n] = carry_s;
}

__global__ __launch_bounds__(256) void dinv_kernel(const int* __restrict__ deg,
                                                   float* __restrict__ dinv, int n) {
    int i = blockIdx.x * blockDim.x + threadIdx.x;
    if (i < n) dinv[i] = rsqrtf((float)deg[i] + 1.0f);
}

// ---------- weight transpose+convert: W [K,N] f32 -> WT [N,K] bf16 ----------
__global__ __launch_bounds__(256) void wt_kernel(const float* __restrict__ W,
                                                 unsigned short* __restrict__ WT,
                                                 int K, int N) {
    int i = blockIdx.x * 256 + threadIdx.x;
    if (i < K * N) {
        int nn = i / K, kk = i % K;
        WT[i] = f2bf(W[(size_t)kk * N + nn]);
    }
}

// ---------- A-tile LDS staging loaders ----------
__device__ __forceinline__ bf16x8 load8_as_bf16(const float* p) {
    float4 lo = *reinterpret_cast<const float4*>(p);
    float4 hi = *reinterpret_cast<const float4*>(p + 4);
    bf16x8 r;
    r[0] = (short)f2bf(lo.x); r[1] = (short)f2bf(lo.y);
    r[2] = (short)f2bf(lo.z); r[3] = (short)f2bf(lo.w);
    r[4] = (short)f2bf(hi.x); r[5] = (short)f2bf(hi.y);
    r[6] = (short)f2bf(hi.z); r[7] = (short)f2bf(hi.w);
    return r;
}
__device__ __forceinline__ bf16x8 load8_as_bf16(const unsigned short* p) {
    return *reinterpret_cast<const bf16x8*>(p);
}

// ---------- MFMA GEMM: C[M, NT*64](bf16, scaled by dinv[row]) = A[M,K] * BT[N,K]^T ----------
// One block = 64 rows x full N (NT 64-col chunks): A is fetched exactly once from HBM.
// BT (<=256KB) is L2-resident across blocks.
template <typename AT, int NT>
__global__ __launch_bounds__(256) void gemm_mfma(const AT* __restrict__ A,
                                                 const unsigned short* __restrict__ BT,
                                                 const float* __restrict__ dinv,
                                                 unsigned short* __restrict__ C,
                                                 int M, int N, int K) {
    constexpr int LP = 40;  // padded LDS row stride (shorts)
    __shared__ short As[64 * LP];
    __shared__ short Bs[NT * 64 * LP];
    const int tid = threadIdx.x;
    const int wave = tid >> 6, lane = tid & 63;
    const int quad = lane >> 4, l16 = lane & 15;
    const int m0 = blockIdx.x * 64;
    const int srow = tid >> 2, sseg = (tid & 3) * 8;
    const int arow = m0 + srow;
    f32x4 acc[NT][4] = {};

    for (int k0 = 0; k0 < K; k0 += 32) {
        bf16x8 av = {};
        if (arow < M) av = load8_as_bf16(A + (size_t)arow * K + k0 + sseg);
        *reinterpret_cast<bf16x8*>(&As[srow * LP + sseg]) = av;
        #pragma unroll
        for (int i = 0; i < NT; ++i) {
            bf16x8 bv = load8_as_bf16(BT + (size_t)(i * 64 + srow) * K + k0 + sseg);
            *reinterpret_cast<bf16x8*>(&Bs[(i * 64 + srow) * LP + sseg]) = bv;
        }
        __syncthreads();
        bf16x8 af = *reinterpret_cast<bf16x8*>(&As[(wave * 16 + l16) * LP + quad * 8]);
        #pragma unroll
        for (int i = 0; i < NT; ++i) {
            #pragma unroll
            for (int ct = 0; ct < 4; ++ct) {
                bf16x8 bfr =
                    *reinterpret_cast<bf16x8*>(&Bs[(i * 64 + ct * 16 + l16) * LP + quad * 8]);
                acc[i][ct] = __builtin_amdgcn_mfma_f32_16x16x32_bf16(af, bfr, acc[i][ct], 0, 0, 0);
            }
        }
        __syncthreads();
    }
    #pragma unroll
    for (int r = 0; r < 4; ++r) {
        int row = m0 + wave * 16 + quad * 4 + r;
        if (row < M) {
            float dv = dinv[row];
            #pragma unroll
            for (int i = 0; i < NT; ++i)
                #pragma unroll
                for (int ct = 0; ct < 4; ++ct)
                    C[(size_t)row * N + i * 64 + ct * 16 + l16] = f2bf(acc[i][ct][r] * dv);
        }
    }
}

// ---------- aggregation: out[i] = relu( dinv[i]*(sum_src hs[src] + hs[i]) + bias ) ----------
template <int LANES>
__global__ __launch_bounds__(256) void agg_kernel(const unsigned short* __restrict__ hs,
                                                  const float* __restrict__ dinv,
                                                  const int* __restrict__ rowptr,
                                                  const int* __restrict__ csr_src,
                                                  const float* __restrict__ bias,
                                                  unsigned short* __restrict__ hout, int n) {
    constexpr int H = LANES * 8;
    constexpr int NPB = 256 / LANES;
    int sub = threadIdx.x / LANES;
    int lane = threadIdx.x % LANES;
    int node = blockIdx.x * NPB + sub;
    if (node >= n) return;
    const unsigned short* tab = hs + (size_t)lane * 8;
    float a[8];
    bf16x8 v0 = *reinterpret_cast<const bf16x8*>(tab + (size_t)node * H);
    #pragma unroll
    for (int j = 0; j < 8; ++j) a[j] = bf2f((unsigned short)v0[j]);
    int e0 = rowptr[node], e1 = rowptr[node + 1];
    int p = e0;
    for (; p + 8 <= e1; p += 8) {
        int s[8];
        #pragma unroll
        for (int u = 0; u < 8; ++u) s[u] = csr_src[p + u];
        bf16x8 w[8];
        #pragma unroll
        for (int u = 0; u < 8; ++u)
            w[u] = *reinterpret_cast<const bf16x8*>(tab + (size_t)s[u] * H);
        #pragma unroll
        for (int u = 0; u < 8; ++u)
            #pragma unroll
            for (int j = 0; j < 8; ++j) a[j] += bf2f((unsigned short)w[u][j]);
    }
    for (; p < e1; ++p) {
        int s = csr_src[p];
        bf16x8 w = *reinterpret_cast<const bf16x8*>(tab + (size_t)s * H);
        #pragma unroll
        for (int j = 0; j < 8; ++j) a[j] += bf2f((unsigned short)w[j]);
    }
    float dv = dinv[node];
    float4 blo = *(reinterpret_cast<const float4*>(bias) + lane * 2);
    float4 bhi = *(reinterpret_cast<const float4*>(bias) + lane * 2 + 1);
    float bvals[8] = {blo.x, blo.y, blo.z, blo.w, bhi.x, bhi.y, bhi.z, bhi.w};
    bf16x8 o;
    #pragma unroll
    for (int j = 0; j < 8; ++j)
        o[j] = (short)f2bf(fmaxf(fmaf(a[j], dv, bvals[j]), 0.f));
    *reinterpret_cast<bf16x8*>(hout + (size_t)node * H + lane * 8) = o;
}

// ---------- head ----------
__global__ __launch_bounds__(256) void head_kernel(const unsigned short* __restrict__ h2,
                                                   const float* __restrict__ Wl,
                                                   const float* __restrict__ bl,
                                                   float* __restrict__ out, int n) {
    __shared__ float w[512];
    __shared__ float bs[4];
    if (threadIdx.x < 4) bs[threadIdx.x] = bl[threadIdx.x];
    for (int i = threadIdx.x; i < 512; i += 256) w[i] = Wl[i];
    __syncthreads();
    int node = blockIdx.x * 256 + threadIdx.x;
    if (node >= n) return;
    float a0 = bs[0], a1 = bs[1], a2 = bs[2], a3 = bs[3];
    const unsigned short* hp = h2 + (size_t)node * 128;
    #pragma unroll
    for (int k4 = 0; k4 < 32; ++k4) {
        ushort4 hv = *reinterpret_cast<const ushort4*>(hp + k4 * 4);
        float h0 = bf2f(hv.x), h1 = bf2f(hv.y), h2v = bf2f(hv.z), h3 = bf2f(hv.w);
        const float* wr = &w[k4 * 16];
        a0 += h0 * wr[0] + h1 * wr[4] + h2v * wr[8]  + h3 * wr[12];
        a1 += h0 * wr[1] + h1 * wr[5] + h2v * wr[9]  + h3 * wr[13];
        a2 += h0 * wr[2] + h1 * wr[6] + h2v * wr[10] + h3 * wr[14];
        a3 += h0 * wr[3] + h1 * wr[7] + h2v * wr[11] + h3 * wr[15];
    }
    float m = fmaxf(fmaxf(a0, a1), fmaxf(a2, a3));
    float s = __expf(a0 - m) + __expf(a1 - m) + __expf(a2 - m) + __expf(a3 - m);
    float lse = m + __logf(s);
    float4 o = make_float4(a0 - lse, a1 - lse, a2 - lse, a3 - lse);
    *(reinterpret_cast<float4*>(out) + node) = o;
}

// ---------- launch ----------
extern "C" void kernel_launch(void* const* d_in, const int* in_sizes, int n_in,
                              void* d_out, int out_size, void* d_ws, size_t ws_size,
                              hipStream_t stream) {
    const float* x  = (const float*)d_in[0];
    const int* eidx = (const int*)d_in[1];
    const float* W1 = (const float*)d_in[2];
    const float* b1 = (const float*)d_in[3];
    const float* W2 = (const float*)d_in[4];
    const float* b2 = (const float*)d_in[5];
    const float* Wl = (const float*)d_in[6];
    const float* bl = (const float*)d_in[7];
    float* out = (float*)d_out;

    const int n = in_sizes[0] / 512;
    const int E = in_sizes[1] / 2;
    const int nb = (n + BKT_NODES - 1) >> BKT_SHIFT;  // 196 for n=100000

    char* ws = (char*)d_ws;
    size_t off = 0;
    auto alloc = [&](size_t bytes) -> void* {
        void* p = ws + off;
        off += (bytes + 255) & ~(size_t)255;
        return p;
    };
    unsigned short* hA  = (unsigned short*)alloc((size_t)n * 256 * 2);
    unsigned short* hB  = (unsigned short*)alloc((size_t)n * 256 * 2);
    unsigned short* W1T = (unsigned short*)alloc((size_t)256 * 512 * 2);
    unsigned short* W2T = (unsigned short*)alloc((size_t)128 * 256 * 2);
    int* deg     = (int*)alloc((size_t)n * 4);
    int* rowptr  = (int*)alloc(((size_t)n + 1) * 4);
    int* cursor  = (int*)alloc((size_t)n * 4);
    float* dinv  = (float*)alloc((size_t)n * 4);
    int* csr_src = (int*)alloc((size_t)E * 4);
    int* gcur    = (int*)alloc((size_t)nb * 4);
    int* gbase   = (int*)alloc((size_t)nb * 4);
    size_t need_binned = off + (size_t)nb * BKT_CAP * 8 + 256;
    uint2* binned = (uint2*)alloc((size_t)nb * BKT_CAP * 8);

    if (need_binned <= ws_size && nb <= 256) {
        hipMemsetAsync(gcur, 0, (size_t)nb * 4, stream);
        int ntiles = (E + BIN_TILE - 1) / BIN_TILE;
        bin_kernel<<<dim3(256), dim3(256), 0, stream>>>(eidx, E, nb, ntiles, gcur, binned);
        bucket_scan_kernel<<<dim3(1), dim3(256), 0, stream>>>(gcur, gbase, rowptr, nb, n);
        bhist_scan_kernel<<<dim3(nb), dim3(256), 0, stream>>>(binned, gcur, gbase, rowptr, dinv, n);
        lfill_kernel<<<dim3(nb), dim3(256), 0, stream>>>(binned, gcur, rowptr, csr_src, n);
    } else {
        hipMemsetAsync(deg, 0, (size_t)n * 4, stream);
        hist_kernel<<<dim3(1024), dim3(256), 0, stream>>>(eidx + E, E, deg);
        scan_kernel<<<dim3(1), dim3(256), 0, stream>>>(deg, rowptr, n);
        dinv_kernel<<<dim3((n + 255) / 256), dim3(256), 0, stream>>>(deg, dinv, n);
        hipMemcpyAsync(cursor, rowptr, (size_t)n * 4, hipMemcpyDeviceToDevice, stream);
        fill_kernel<<<dim3((E + 255) / 256), dim3(256), 0, stream>>>(eidx, E, cursor, csr_src);
    }

    // Weight prep
    wt_kernel<<<dim3((512 * 256 + 255) / 256), dim3(256), 0, stream>>>(W1, W1T, 512, 256);
    wt_kernel<<<dim3((256 * 128 + 255) / 256), dim3(256), 0, stream>>>(W2, W2T, 256, 128);

    const int mblocks = (n + 63) / 64;

    // Layer 1: hs1 = (x@W1)*dinv -> agg (H=256)
    gemm_mfma<float, 4><<<dim3(mblocks), dim3(256), 0, stream>>>(
        x, W1T, dinv, hA, n, 256, 512);
    agg_kernel<32><<<dim3((n + 7) / 8), dim3(256), 0, stream>>>(
        hA, dinv, rowptr, csr_src, b1, hB, n);

    // Layer 2: hs2 = (h1@W2)*dinv -> agg (H=128)
    gemm_mfma<unsigned short, 2><<<dim3(mblocks), dim3(256), 0, stream>>>(
        hB, W2T, dinv, hA, n, 128, 256);
    agg_kernel<16><<<dim3((n + 15) / 16), dim3(256), 0, stream>>>(
        hA, dinv, rowptr, csr_src, b2, hB, n);

    // Head: log_softmax(h2 @ Wl + bl)
    head_kernel<<<dim3((n + 255) / 256), dim3(256), 0, stream>>>(hB, Wl, bl, out, n);
}